// Round 2
// baseline (1204.962 us; speedup 1.0000x reference)
//
#include <hip/hip_runtime.h>

#define NEGV -1e9f

// Problem dims (fixed by the reference)
#define BB 32
#define CC 192
#define TXD 512
#define TYD 2048

// d_out (f32 element offsets) — final output layout
#define E_DUR   0
#define E_ATTN  16384
#define E_MP    33570816
#define E_LS    46153728
#define E_TOTAL 58736640

// Scratch placed inside d_out (regions written only by late kernels):
//  L    -> attn region  [E_ATTN, E_ATTN+33554432)  f32, exactly fills it
//  A    -> mp region    [E_MP, +6291456) f32
//  dirs -> mp region    [E_MP+6291456, +1048576) (u8, 4 MiB)
//  l14  -> mp region    [E_MP+7340032, +16384) f32
// Order: k_gemm/k_dp read these; k_attn (writes attn) and k_gather (writes
// mp/ls) run strictly after k_dp on the same stream.
#define E_L    E_ATTN
#define E_A    E_MP
#define E_DIRS (E_MP + 6291456)
#define E_L14  (E_MP + 7340032)

// d_ws layout (bytes) — tiny persistent scratch only
#define WS_PATH 0ull           // u16 [B][2048] = 131072 B
#define WS_YST  131072ull      // u32 [B][513]  = 65664 B
#define WS_TXTY 196864ull      // u32 [64]      = 256 B
#define WS_NEED 262144ull

// ---------------- K0a: A = [o_scale ; m*o_scale], plus t_x/t_y ----------------
__global__ __launch_bounds__(256) void k_prep(const float* __restrict__ logs_p,
                                              const float* __restrict__ m_p,
                                              const int* __restrict__ xl,
                                              const int* __restrict__ yl,
                                              float* __restrict__ A,
                                              unsigned* __restrict__ txty) {
    int idx = blockIdx.x * 256 + threadIdx.x;  // covers 32*192*512 exactly
    float ls = logs_p[idx];
    float m  = m_p[idx];
    float o  = expf(-2.0f * ls);
    int b = idx / (CC * TXD);
    int r = idx - b * (CC * TXD);
    A[(size_t)b * (2 * CC * TXD) + r] = o;
    A[(size_t)b * (2 * CC * TXD) + (CC * TXD) + r] = m * o;
    if (idx < BB) {
        int txv = min(max(xl[idx], 2), TXD);
        int tyv = min(max(yl[idx], 2), TYD);
        tyv = max(tyv, txv);
        txty[idx] = (unsigned)txv;
        txty[BB + idx] = (unsigned)tyv;
    }
}

// ---------------- K0b: l14[b][t] = sum_c (-.5log2pi - logs - .5 m^2 o) ----------------
__global__ __launch_bounds__(128) void k_l14(const float* __restrict__ logs_p,
                                             const float* __restrict__ m_p,
                                             float* __restrict__ l14) {
    int t = blockIdx.x * 128 + threadIdx.x;  // grid.x = 4
    int b = blockIdx.y;
    float acc = 0.0f;
    for (int c = 0; c < CC; ++c) {
        float ls = logs_p[((size_t)b * CC + c) * TXD + t];
        float m  = m_p[((size_t)b * CC + c) * TXD + t];
        float o  = expf(-2.0f * ls);
        acc += -0.918938533204672741780329736406f - ls - 0.5f * m * m * o;
    }
    l14[b * TXD + t] = acc;
}

// ---------------- K1: L[b][s][t] = masked logp (f32 vector GEMM) ----------------
// 128x128 tile, 256 threads, 8x8 micro-tile (split 4+4 with stride 64)
__global__ __launch_bounds__(256) void k_gemm(const float* __restrict__ z_p,
                                              const float* __restrict__ A,
                                              const float* __restrict__ l14,
                                              const unsigned* __restrict__ txty,
                                              float* __restrict__ L) {
    __shared__ float zt[8][128];
    __shared__ float a1t[8][128];
    __shared__ float a2t[8][128];
    __shared__ float l14s[128];
    int bx = blockIdx.x, b = blockIdx.y;
    int t0 = (bx & 3) * 128, s0 = (bx >> 2) * 128;
    int tid = threadIdx.x;
    int tx16 = tid & 15, ty16 = tid >> 4;
    if (tid < 128) l14s[tid] = l14[b * TXD + t0 + tid];
    float acc[2][2][4][4] = {};
    int row = tid >> 5, col4 = (tid & 31) * 4;
    const float* zsrc  = z_p + ((size_t)b * CC + row) * TYD + s0 + col4;
    const float* a1src = A + ((size_t)b * (2 * CC) + row) * TXD + t0 + col4;

    for (int c0 = 0; c0 < CC; c0 += 8) {
        __syncthreads();
        *(float4*)&zt[row][col4]  = *(const float4*)(zsrc + (size_t)c0 * TYD);
        *(float4*)&a1t[row][col4] = *(const float4*)(a1src + (size_t)c0 * TXD);
        *(float4*)&a2t[row][col4] = *(const float4*)(a1src + (size_t)(c0 + CC) * TXD);
        __syncthreads();
#pragma unroll
        for (int kk = 0; kk < 8; ++kk) {
            float4 z0  = *(float4*)&zt[kk][ty16 * 4];
            float4 z1  = *(float4*)&zt[kk][ty16 * 4 + 64];
            float4 b10 = *(float4*)&a1t[kk][tx16 * 4];
            float4 b11 = *(float4*)&a1t[kk][tx16 * 4 + 64];
            float4 b20 = *(float4*)&a2t[kk][tx16 * 4];
            float4 b21 = *(float4*)&a2t[kk][tx16 * 4 + 64];
            float zs[2][4]  = {{z0.x, z0.y, z0.z, z0.w}, {z1.x, z1.y, z1.z, z1.w}};
            float a1s[2][4] = {{b10.x, b10.y, b10.z, b10.w}, {b11.x, b11.y, b11.z, b11.w}};
            float a2s[2][4] = {{b20.x, b20.y, b20.z, b20.w}, {b21.x, b21.y, b21.z, b21.w}};
#pragma unroll
            for (int ii = 0; ii < 2; ++ii)
#pragma unroll
                for (int di = 0; di < 4; ++di) {
                    float zv = zs[ii][di];
                    float zzv = -0.5f * zv * zv;
#pragma unroll
                    for (int jj = 0; jj < 2; ++jj)
#pragma unroll
                        for (int dj = 0; dj < 4; ++dj)
                            acc[ii][jj][di][dj] += zzv * a1s[jj][dj] + zv * a2s[jj][dj];
                }
        }
    }
    int txb = (int)txty[b], tyb = (int)txty[BB + b];
#pragma unroll
    for (int ii = 0; ii < 2; ++ii)
#pragma unroll
        for (int di = 0; di < 4; ++di) {
            int s = s0 + ty16 * 4 + ii * 64 + di;
            bool sv = s < tyb;
#pragma unroll
            for (int jj = 0; jj < 2; ++jj) {
                int tb = tx16 * 4 + jj * 64;
                float4 o;
                float* ov = (float*)&o;
#pragma unroll
                for (int dj = 0; dj < 4; ++dj) {
                    int t = t0 + tb + dj;
                    ov[dj] = (sv && t < txb) ? (acc[ii][jj][di][dj] + l14s[tb + dj]) : NEGV;
                }
                *(float4*)&L[((size_t)b * TYD + s) * TXD + t0 + tb] = o;
            }
        }
}

// ---------------- K2: Viterbi DP + chunked backtrack + durations/prefix ----------------
__global__ __launch_bounds__(64) void k_dp(const float* __restrict__ L,
                                           const unsigned* __restrict__ txty,
                                           unsigned char* __restrict__ dirsG,
                                           unsigned short* __restrict__ pathG,
                                           unsigned* __restrict__ ystartG,
                                           float* __restrict__ outDur) {
    __shared__ unsigned char dmaps[32 * 512];  // per-64-row-chunk origin deltas
    __shared__ unsigned short path[TYD];
    __shared__ unsigned cnt[513];
    __shared__ unsigned ebuf[32];
    int b = blockIdx.x, lane = threadIdx.x;
    int tx = (int)txty[b], ty = (int)txty[BB + b];
    const float* Lb = L + (size_t)b * (TYD * TXD);
    unsigned char* dG = dirsG + (size_t)b * (TYD * 64);

    float v[8];
    unsigned p[8];
    {
        float4 r0 = *(const float4*)(Lb + lane * 8);
        float4 r1 = *(const float4*)(Lb + lane * 8 + 4);
        float lp[8] = {r0.x, r0.y, r0.z, r0.w, r1.x, r1.y, r1.z, r1.w};
#pragma unroll
        for (int i = 0; i < 8; ++i) {
            int x = lane * 8 + i;
            v[i] = (x == 0) ? lp[i] : NEGV;
            p[i] = (unsigned)x;
        }
    }
    dG[lane] = 0;  // dirs row 0 = zeros

    // 8-deep register prefetch of L rows (covers ~800cy HBM latency; static idx)
    float4 ra[8], rb[8];
#pragma unroll
    for (int k = 0; k < 8; ++k) {
        int yy = 1 + k; if (yy > TYD - 1) yy = TYD - 1;
        ra[k] = *(const float4*)(Lb + (size_t)yy * TXD + lane * 8);
        rb[k] = *(const float4*)(Lb + (size_t)yy * TXD + lane * 8 + 4);
    }

    for (int yb = 1; yb < ty; yb += 8) {
#pragma unroll
        for (int k = 0; k < 8; ++k) {
            int y = yb + k;
            if (y < ty) {  // wave-uniform
                float cur[8] = {ra[k].x, ra[k].y, ra[k].z, ra[k].w,
                                rb[k].x, rb[k].y, rb[k].z, rb[k].w};
                float vp0 = __shfl_up(v[7], 1);
                unsigned pp0 = (unsigned)__shfl_up((int)p[7], 1);
                if (lane == 0) vp0 = NEGV;
                unsigned bits = 0;
#pragma unroll
                for (int i = 7; i >= 0; --i) {  // descending: reads old v[i-1]/p[i-1]
                    float vp = (i == 0) ? vp0 : v[i - 1];
                    unsigned pp = (i == 0) ? pp0 : p[i - 1];
                    bool d = vp > v[i];
                    v[i] = cur[i] + (d ? vp : v[i]);
                    p[i] = d ? pp : p[i];
                    bits |= (d ? 1u : 0u) << i;
                }
                dG[y * 64 + lane] = (unsigned char)bits;
                if ((y & 63) == 0) {  // chunk start: reset provenance
#pragma unroll
                    for (int i = 0; i < 8; ++i) p[i] = (unsigned)(lane * 8 + i);
                }
                if ((y & 63) == 63) {  // chunk end: store origin map as delta
                    int c = y >> 6;
#pragma unroll
                    for (int i = 0; i < 8; ++i)
                        dmaps[c * 512 + lane * 8 + i] =
                            (unsigned char)((unsigned)(lane * 8 + i) - p[i]);
                }
            }
            int yp = yb + k + 8; if (yp > TYD - 1) yp = TYD - 1;
            ra[k] = *(const float4*)(Lb + (size_t)yp * TXD + lane * 8);
            rb[k] = *(const float4*)(Lb + (size_t)yp * TXD + lane * 8 + 4);
        }
    }
    __syncthreads();

    int c0 = (ty - 1) >> 6;
    if (lane == 0) {
        int pos = tx - 1;
        for (int y = ty - 1; y >= (c0 << 6); --y) {  // top partial chunk
            path[y] = (unsigned short)pos;
            unsigned bv = dG[y * 64 + (pos >> 3)];
            pos -= (int)((bv >> (pos & 7)) & 1u);
        }
        for (int c = c0 - 1; c >= 0; --c) {  // chunk-boundary resolution via dmaps
            ebuf[c] = (unsigned)pos;
            int P = pos - (int)dmaps[c * 512 + pos];
            unsigned bv = dG[(c << 6) * 64 + (P >> 3)];
            pos = P - (int)((bv >> (P & 7)) & 1u);
        }
    }
    __syncthreads();
    if (lane < c0) {  // parallel per-chunk chases
        int c = lane;
        int pos = (int)ebuf[c];
        for (int y = (c << 6) + 63; y >= (c << 6); --y) {
            path[y] = (unsigned short)pos;
            unsigned bv = dG[y * 64 + (pos >> 3)];
            pos -= (int)((bv >> (pos & 7)) & 1u);
        }
    }
    __syncthreads();

    for (int i = lane; i < 513; i += 64) cnt[i] = 0;
    __syncthreads();
    for (int y = lane; y < ty; y += 64) atomicAdd(&cnt[path[y]], 1u);
    __syncthreads();

    unsigned c8[8], lsum = 0;
#pragma unroll
    for (int i = 0; i < 8; ++i) {
        c8[i] = cnt[lane * 8 + i];
        lsum += c8[i];
    }
    unsigned incl = lsum;
    for (int d = 1; d < 64; d <<= 1) {
        unsigned t = (unsigned)__shfl_up((int)incl, d);
        if (lane >= d) incl += t;
    }
    unsigned run = incl - lsum;
#pragma unroll
    for (int i = 0; i < 8; ++i) {
        int x = lane * 8 + i;
        ystartG[b * 513 + x] = run;
        outDur[(size_t)b * TXD + x] = (float)c8[i];
        run += c8[i];
    }
    if (lane == 0) ystartG[b * 513 + 512] = (unsigned)ty;
    for (int y = lane; y < ty; y += 64) pathG[b * TYD + y] = path[y];
}

// ---------------- K3: dense attn rows (f32 0/1) ----------------
__global__ __launch_bounds__(64) void k_attn(const unsigned* __restrict__ ystartG,
                                             float* __restrict__ out) {
    int x = blockIdx.x, b = blockIdx.y, lane = threadIdx.x;
    unsigned s0 = ystartG[b * 513 + x];
    unsigned s1 = ystartG[b * 513 + x + 1];
    float* row = out + E_ATTN + ((size_t)(b * TXD + x)) * TYD + lane * 32;
#pragma unroll
    for (int k = 0; k < 8; ++k) {
        unsigned y0 = (unsigned)(lane * 32 + k * 4);
        float4 o;
        o.x = (y0 + 0 >= s0 && y0 + 0 < s1) ? 1.0f : 0.0f;
        o.y = (y0 + 1 >= s0 && y0 + 1 < s1) ? 1.0f : 0.0f;
        o.z = (y0 + 2 >= s0 && y0 + 2 < s1) ? 1.0f : 0.0f;
        o.w = (y0 + 3 >= s0 && y0 + 3 < s1) ? 1.0f : 0.0f;
        *(float4*)(row + k * 4) = o;
    }
}

// ---------------- K4: m_p_dur / logs_p_dur gathers (f32) ----------------
__global__ __launch_bounds__(256) void k_gather(const float* __restrict__ m_p,
                                                const float* __restrict__ logs_p,
                                                const unsigned short* __restrict__ pathG,
                                                const unsigned* __restrict__ txty,
                                                float* __restrict__ out) {
    __shared__ unsigned short px[64];
    int yc = blockIdx.x, b = blockIdx.y;
    int y0 = yc * 64, tid = threadIdx.x;
    int lane = tid & 63, w = tid >> 6;
    int ty = (int)txty[BB + b];
    if (tid < 64) px[tid] = (y0 + tid < ty) ? pathG[b * TYD + y0 + tid] : 0;
    __syncthreads();
    bool act = (y0 + lane) < ty;
    int xx = (int)px[lane];
    for (int c = w; c < CC; c += 4) {
        float mv = act ? m_p[((size_t)b * CC + c) * TXD + xx] : 0.0f;
        float lv = act ? logs_p[((size_t)b * CC + c) * TXD + xx] : 0.0f;
        size_t oidx = ((size_t)(b * CC + c)) * TYD + y0 + lane;
        out[E_MP + oidx] = mv;
        out[E_LS + oidx] = lv;
    }
}

extern "C" void kernel_launch(void* const* d_in, const int* in_sizes, int n_in,
                              void* d_out, int out_size, void* d_ws, size_t ws_size,
                              hipStream_t stream) {
    if (out_size < E_TOTAL) return;   // layout assumption violated; fail visibly
    if (ws_size < WS_NEED) return;    // need only 256 KiB of ws
    const float* z_p    = (const float*)d_in[0];
    const float* m_p    = (const float*)d_in[1];
    const float* logs_p = (const float*)d_in[2];
    const int* xl       = (const int*)d_in[3];
    const int* yl       = (const int*)d_in[4];
    float* out = (float*)d_out;
    char* ws = (char*)d_ws;

    // big scratch lives in late-written d_out regions
    float* L              = out + E_L;
    float* A              = out + E_A;
    unsigned char* dirsG  = (unsigned char*)(out + E_DIRS);
    float* l14            = out + E_L14;
    // tiny persistent scratch in d_ws
    unsigned short* pathG = (unsigned short*)(ws + WS_PATH);
    unsigned* ystartG     = (unsigned*)(ws + WS_YST);
    unsigned* txty        = (unsigned*)(ws + WS_TXTY);

    hipLaunchKernelGGL(k_prep, dim3(12288), dim3(256), 0, stream, logs_p, m_p, xl, yl, A, txty);
    hipLaunchKernelGGL(k_l14, dim3(4, BB), dim3(128), 0, stream, logs_p, m_p, l14);
    hipLaunchKernelGGL(k_gemm, dim3(64, BB), dim3(256), 0, stream, z_p, A, l14, txty, L);
    hipLaunchKernelGGL(k_dp, dim3(BB), dim3(64), 0, stream, L, txty, dirsG, pathG, ystartG, out + E_DUR);
    hipLaunchKernelGGL(k_attn, dim3(TXD, BB), dim3(64), 0, stream, ystartG, out);
    hipLaunchKernelGGL(k_gather, dim3(TYD / 64, BB), dim3(256), 0, stream, m_p, logs_p, pathG, txty, out);
}

// Round 3
// 692.260 us; speedup vs baseline: 1.7406x; 1.7406x over previous
//
#include <hip/hip_runtime.h>

#define NEGV -1e9f
#define BB 32
#define CC 192
#define TXD 512
#define TYD 2048

// d_out layout (f32 elements)
#define E_DUR   0
#define E_ATTN  16384
#define E_MP    33570816
#define E_LS    46153728
#define E_TOTAL 58736640

// Scratch inside d_out (stream-ordered reuse):
//  l14  -> DUR region (16384 f32, exact); k_dp overwrites at the end
//  L    -> ATTN region (exact); k_attn overwrites at the end
//  Zpl  -> MP region (exact): fp16 planes [B][4][1024][192], one s-half at a time
//  Bpl  -> LS region (first 6291456 f32): fp16 planes [B][4][512][192]
//  dirs -> LS region + 6291456 f32 (4 MiB u8); k_gather overwrites LS last
#define OFF_DIRS 6291456

// d_ws (bytes): tiny persistent scratch
#define WS_PATH 0ull
#define WS_YST  131072ull
#define WS_TXTY 196864ull
#define WS_NEED 262144ull

typedef _Float16 f16x8 __attribute__((ext_vector_type(8)));
typedef float f32x4 __attribute__((ext_vector_type(4)));

__device__ __forceinline__ void glds16(const void* g, void* l) {
    __builtin_amdgcn_global_load_lds((const __attribute__((address_space(1))) unsigned*)g,
                                     (__attribute__((address_space(3))) unsigned*)l, 16, 0, 0);
}
__device__ __forceinline__ unsigned packh(_Float16 a, _Float16 b) {
    union { _Float16 h[2]; unsigned u; } x; x.h[0] = a; x.h[1] = b; return x.u;
}

// ---------------- K0: B-side fp16 planes [b][4][t][c] + l14 + txty ----------------
__global__ __launch_bounds__(256) void k_prepB(const float* __restrict__ logs_p,
                                               const float* __restrict__ m_p,
                                               const int* __restrict__ xl,
                                               const int* __restrict__ yl,
                                               _Float16* __restrict__ Bpl,
                                               float* __restrict__ l14,
                                               unsigned* __restrict__ txty) {
    __shared__ float lst[CC][33];
    __shared__ float mst[CC][33];
    __shared__ float p14[8][32];
    int b = blockIdx.y, t0 = blockIdx.x * 32, tid = threadIdx.x;
    const float* lsb = logs_p + (size_t)b * CC * TXD + t0;
    const float* mb  = m_p    + (size_t)b * CC * TXD + t0;
#pragma unroll
    for (int i = 0; i < 24; ++i) {
        int u = i * 256 + tid, c = u >> 5, t = u & 31;
        lst[c][t] = lsb[(size_t)c * TXD + t];
        mst[c][t] = mb [(size_t)c * TXD + t];
    }
    __syncthreads();
    { int q = tid >> 5, t = tid & 31; float s = 0.f;
      for (int c = q * 24; c < q * 24 + 24; ++c) {
          float ls = lst[c][t], m = mst[c][t];
          float o = expf(-2.f * ls);
          s += -0.918938533204672741780329736406f - ls - 0.5f * m * m * o;
      }
      p14[q][t] = s; }
    __syncthreads();
    if (tid < 32) {
        float s = 0.f;
#pragma unroll
        for (int q = 0; q < 8; ++q) s += p14[q][tid];
        l14[b * TXD + t0 + tid] = s;
    }
    _Float16* Bb = Bpl + (size_t)b * (4 * TXD * CC);
    unsigned* B0 = (unsigned*)(Bb);
    unsigned* B1 = (unsigned*)(Bb + (size_t)1 * TXD * CC);
    unsigned* B2 = (unsigned*)(Bb + (size_t)2 * TXD * CC);
    unsigned* B3 = (unsigned*)(Bb + (size_t)3 * TXD * CC);
#pragma unroll
    for (int i = 0; i < 12; ++i) {
        int u = i * 256 + tid, t = u / 96, cp = u - t * 96, c = cp * 2;
        float ls0 = lst[c][t], ls1 = lst[c + 1][t];
        float m0 = mst[c][t], m1 = mst[c + 1][t];
        float o0 = expf(-2.f * ls0), o1 = expf(-2.f * ls1);
        float w0 = m0 * o0, w1 = m1 * o1;
        _Float16 oh0 = (_Float16)o0, oh1 = (_Float16)o1;
        _Float16 ol0 = (_Float16)(o0 - (float)oh0), ol1 = (_Float16)(o1 - (float)oh1);
        _Float16 wh0 = (_Float16)w0, wh1 = (_Float16)w1;
        _Float16 wl0 = (_Float16)(w0 - (float)wh0), wl1 = (_Float16)(w1 - (float)wh1);
        int ui = ((t0 + t) * CC + c) >> 1;
        B0[ui] = packh(oh0, oh1);
        B1[ui] = packh(ol0, ol1);
        B2[ui] = packh(wh0, wh1);
        B3[ui] = packh(wl0, wl1);
    }
    if (blockIdx.x == 0 && blockIdx.y == 0 && tid < BB) {
        int txv = min(max(xl[tid], 2), TXD);
        int tyv = min(max(yl[tid], 2), TYD);
        tyv = max(tyv, txv);
        txty[tid] = (unsigned)txv;
        txty[BB + tid] = (unsigned)tyv;
    }
}

// ---------------- K1: Z-side fp16 planes [b][4][sHalf][c] (one 1024-row half) ----------------
__global__ __launch_bounds__(256) void k_prepZ(const float* __restrict__ z_p,
                                               _Float16* __restrict__ Zpl, int sBase) {
    __shared__ float zt[CC][65];
    int b = blockIdx.y, s0 = blockIdx.x * 64, tid = threadIdx.x;
    const float* zb = z_p + (size_t)b * CC * TYD + sBase + s0;
#pragma unroll
    for (int i = 0; i < 48; ++i) {
        int u = i * 256 + tid, c = u >> 6, s = u & 63;
        zt[c][s] = zb[(size_t)c * TYD + s];
    }
    __syncthreads();
    _Float16* Zb = Zpl + (size_t)b * (4 * 1024 * CC);
    unsigned* Z0 = (unsigned*)(Zb);
    unsigned* Z1 = (unsigned*)(Zb + (size_t)1 * 1024 * CC);
    unsigned* Z2 = (unsigned*)(Zb + (size_t)2 * 1024 * CC);
    unsigned* Z3 = (unsigned*)(Zb + (size_t)3 * 1024 * CC);
#pragma unroll
    for (int i = 0; i < 24; ++i) {
        int u = i * 256 + tid, s = u / 96, cp = u - s * 96, c = cp * 2;
        float z0 = zt[c][s], z1 = zt[c + 1][s];
        float P0 = -0.5f * z0 * z0, P1 = -0.5f * z1 * z1;
        _Float16 ph0 = (_Float16)P0, ph1 = (_Float16)P1;
        _Float16 pl0 = (_Float16)(P0 - (float)ph0), pl1 = (_Float16)(P1 - (float)ph1);
        _Float16 zh0 = (_Float16)z0, zh1 = (_Float16)z1;
        _Float16 zl0 = (_Float16)(z0 - (float)zh0), zl1 = (_Float16)(z1 - (float)zh1);
        int ui = ((s0 + s) * CC + c) >> 1;
        Z0[ui] = packh(ph0, ph1);
        Z1[ui] = packh(pl0, pl1);
        Z2[ui] = packh(zh0, zh1);
        Z3[ui] = packh(zl0, zl1);
    }
}

// ---------------- K2: fp16x3 MFMA GEMM -> L (one 1024-row s-half) ----------------
// block tile 256(s) x 128(t), 4 waves (each 64x128), K=192 x 6 plane-pass
__global__ __launch_bounds__(256, 2) void k_mm(const _Float16* __restrict__ Zpl,
                                               const _Float16* __restrict__ Bpl,
                                               const float* __restrict__ l14,
                                               const unsigned* __restrict__ txty,
                                               float* __restrict__ L, int sBase) {
    __shared__ __align__(16) char As[32768];  // [256][64] fp16, slot-swizzled
    __shared__ __align__(16) char Bs[16384];  // [128][64] fp16
    int bid = blockIdx.x;
    int xcd = bid & 7, idx = bid >> 3;
    int b = xcd + 8 * (idx >> 4);   // XCD-grouped: each XCD works 4 b's, 16 tiles each
    int tile = idx & 15;
    int s0 = (tile >> 2) * 256, t0 = (tile & 3) * 128;
    int txb = (int)txty[b], tyb = (int)txty[BB + b];
    int sg0 = sBase + s0;
    if (sg0 >= tyb) return;  // rows never read by DP; k_attn overwrites later
    int tid = threadIdx.x, l = tid & 63, w = tid >> 6;
    float* Lt = L + ((size_t)b * TYD + sg0) * TXD + t0;
    if (t0 >= txb) {  // fully col-masked: NEGV fill, no K-loop
#pragma unroll
        for (int i = 0; i < 32; ++i) {
            int u = i * 256 + tid, r = u >> 5, c4 = (u & 31) * 4;
            *(float4*)(Lt + (size_t)r * TXD + c4) = make_float4(NEGV, NEGV, NEGV, NEGV);
        }
        return;
    }
    f32x4 acc[4][8];
#pragma unroll
    for (int i = 0; i < 4; ++i)
#pragma unroll
        for (int j = 0; j < 8; ++j) acc[i][j] = (f32x4){0.f, 0.f, 0.f, 0.f};

    const char* Zb = (const char*)(Zpl + (size_t)b * (4 * 1024 * CC));
    const char* Bb = (const char*)(Bpl + (size_t)b * (4 * TXD * CC));
    int lrow = l >> 3;
    int gOff = lrow * 384 + (((l & 7) ^ lrow) * 16);  // pre-swizzled global source slot
    int arow_off = (w * 64 + (l & 15)) * 128;
    int brow_off = (l & 15) * 128;
    int slot0 = (((l >> 4) + 0) ^ (l & 7)) * 16;
    int slot1 = (((l >> 4) + 4) ^ (l & 7)) * 16;

    for (int pass = 0; pass < 6; ++pass) {
        // pairs: (Ph,oh)(Ph,ol)(Pl,oh)(zh,wh)(zh,wl)(zl,wh)
        int ap = ((pass >= 3) ? 2 : 0) + ((pass == 2 || pass == 5) ? 1 : 0);
        int bp = ((pass >= 3) ? 2 : 0) + ((pass == 1 || pass == 4) ? 1 : 0);
        const char* Zp = Zb + ((size_t)ap * 1024 + s0) * 384;
        const char* Bp = Bb + ((size_t)bp * TXD + t0) * 384;
        for (int k0 = 0; k0 < 384; k0 += 128) {  // 64-k slices (byte offset in row)
            __syncthreads();
#pragma unroll
            for (int j = 0; j < 8; ++j) {
                int c = w * 8 + j;
                glds16(Zp + (size_t)c * (8 * 384) + gOff + k0, As + c * 1024);
            }
#pragma unroll
            for (int j = 0; j < 4; ++j) {
                int c = w * 4 + j;
                glds16(Bp + (size_t)c * (8 * 384) + gOff + k0, Bs + c * 1024);
            }
            __syncthreads();
#pragma unroll
            for (int ks = 0; ks < 2; ++ks) {
                int so = ks ? slot1 : slot0;
                f16x8 av[4], bv[8];
#pragma unroll
                for (int fm = 0; fm < 4; ++fm)
                    av[fm] = *(const f16x8*)(As + arow_off + fm * (16 * 128) + so);
#pragma unroll
                for (int fn = 0; fn < 8; ++fn)
                    bv[fn] = *(const f16x8*)(Bs + brow_off + fn * (16 * 128) + so);
#pragma unroll
                for (int fm = 0; fm < 4; ++fm)
#pragma unroll
                    for (int fn = 0; fn < 8; ++fn)
                        acc[fm][fn] = __builtin_amdgcn_mfma_f32_16x16x32_f16(
                            av[fm], bv[fn], acc[fm][fn], 0, 0, 0);
            }
        }
    }
    float l14v[8];
#pragma unroll
    for (int fn = 0; fn < 8; ++fn) l14v[fn] = l14[b * TXD + t0 + fn * 16 + (l & 15)];
    int sb = sg0 + w * 64 + (l >> 4) * 4;
    int tcol = t0 + (l & 15);
#pragma unroll
    for (int fm = 0; fm < 4; ++fm)
#pragma unroll
        for (int r = 0; r < 4; ++r) {
            int sg = sb + fm * 16 + r;
            bool sv = sg < tyb;
            float* Lrow = L + ((size_t)b * TYD + sg) * TXD;
#pragma unroll
            for (int fn = 0; fn < 8; ++fn) {
                int t = tcol + fn * 16;
                Lrow[t] = (sv && t < txb) ? (acc[fm][fn][r] + l14v[fn]) : NEGV;
            }
        }
}

// ---------------- K3: Viterbi DP + chunked backtrack + durations/prefix ----------------
__global__ __launch_bounds__(64) void k_dp(const float* __restrict__ L,
                                           const unsigned* __restrict__ txty,
                                           unsigned char* __restrict__ dirsG,
                                           unsigned short* __restrict__ pathG,
                                           unsigned* __restrict__ ystartG,
                                           float* __restrict__ outDur) {
    __shared__ unsigned char dmaps[32 * 512];
    __shared__ unsigned short path[TYD];
    __shared__ unsigned cnt[513];
    __shared__ unsigned ebuf[32];
    int b = blockIdx.x, lane = threadIdx.x;
    int tx = (int)txty[b], ty = (int)txty[BB + b];
    const float* Lb = L + (size_t)b * (TYD * TXD);
    unsigned char* dG = dirsG + (size_t)b * (TYD * 64);

    float v[8];
    unsigned p[8];
    {
        float4 r0 = *(const float4*)(Lb + lane * 8);
        float4 r1 = *(const float4*)(Lb + lane * 8 + 4);
        float lp[8] = {r0.x, r0.y, r0.z, r0.w, r1.x, r1.y, r1.z, r1.w};
#pragma unroll
        for (int i = 0; i < 8; ++i) {
            int x = lane * 8 + i;
            v[i] = (x == 0) ? lp[i] : NEGV;
            p[i] = (unsigned)x;
        }
    }
    dG[lane] = 0;

    // 16-deep register prefetch (covers ~900cy HBM latency; static indexing)
    float4 ra[16], rb[16];
#pragma unroll
    for (int k = 0; k < 16; ++k) {
        int yy = 1 + k;
        ra[k] = *(const float4*)(Lb + (size_t)yy * TXD + lane * 8);
        rb[k] = *(const float4*)(Lb + (size_t)yy * TXD + lane * 8 + 4);
    }

    for (int yb = 1; yb < ty; yb += 16) {
#pragma unroll
        for (int k = 0; k < 16; ++k) {
            int y = yb + k;
            if (y < ty) {  // wave-uniform
                float cur[8] = {ra[k].x, ra[k].y, ra[k].z, ra[k].w,
                                rb[k].x, rb[k].y, rb[k].z, rb[k].w};
                float vp0 = __shfl_up(v[7], 1);
                unsigned pp0 = (unsigned)__shfl_up((int)p[7], 1);
                if (lane == 0) vp0 = NEGV;
                unsigned bits = 0;
#pragma unroll
                for (int i = 7; i >= 0; --i) {  // descending: reads old v[i-1]/p[i-1]
                    float vp = (i == 0) ? vp0 : v[i - 1];
                    unsigned pp = (i == 0) ? pp0 : p[i - 1];
                    bool d = vp > v[i];
                    v[i] = cur[i] + (d ? vp : v[i]);
                    p[i] = d ? pp : p[i];
                    bits |= (d ? 1u : 0u) << i;
                }
                dG[y * 64 + lane] = (unsigned char)bits;
                if ((y & 63) == 0) {  // chunk start: reset provenance
#pragma unroll
                    for (int i = 0; i < 8; ++i) p[i] = (unsigned)(lane * 8 + i);
                }
                if ((y & 63) == 63) {  // chunk end: origin map as delta
                    int c = y >> 6;
#pragma unroll
                    for (int i = 0; i < 8; ++i)
                        dmaps[c * 512 + lane * 8 + i] =
                            (unsigned char)((unsigned)(lane * 8 + i) - p[i]);
                }
            }
            int yp = yb + k + 16; if (yp > TYD - 1) yp = TYD - 1;
            ra[k] = *(const float4*)(Lb + (size_t)yp * TXD + lane * 8);
            rb[k] = *(const float4*)(Lb + (size_t)yp * TXD + lane * 8 + 4);
        }
    }
    __syncthreads();

    int c0 = (ty - 1) >> 6;
    if (lane == 0) {
        int pos = tx - 1;
        for (int y = ty - 1; y >= (c0 << 6); --y) {  // top partial chunk
            path[y] = (unsigned short)pos;
            unsigned bv = dG[y * 64 + (pos >> 3)];
            pos -= (int)((bv >> (pos & 7)) & 1u);
        }
        for (int c = c0 - 1; c >= 0; --c) {  // chunk-boundary resolution
            ebuf[c] = (unsigned)pos;
            int P = pos - (int)dmaps[c * 512 + pos];
            unsigned bv = dG[(c << 6) * 64 + (P >> 3)];
            pos = P - (int)((bv >> (P & 7)) & 1u);
        }
    }
    __syncthreads();
    if (lane < c0) {  // parallel per-chunk chases
        int c = lane;
        int pos = (int)ebuf[c];
        for (int y = (c << 6) + 63; y >= (c << 6); --y) {
            path[y] = (unsigned short)pos;
            unsigned bv = dG[y * 64 + (pos >> 3)];
            pos -= (int)((bv >> (pos & 7)) & 1u);
        }
    }
    __syncthreads();

    for (int i = lane; i < 513; i += 64) cnt[i] = 0;
    __syncthreads();
    for (int y = lane; y < ty; y += 64) atomicAdd(&cnt[path[y]], 1u);
    __syncthreads();

    unsigned c8[8], lsum = 0;
#pragma unroll
    for (int i = 0; i < 8; ++i) {
        c8[i] = cnt[lane * 8 + i];
        lsum += c8[i];
    }
    unsigned incl = lsum;
    for (int d = 1; d < 64; d <<= 1) {
        unsigned t = (unsigned)__shfl_up((int)incl, d);
        if (lane >= d) incl += t;
    }
    unsigned run = incl - lsum;
#pragma unroll
    for (int i = 0; i < 8; ++i) {
        int x = lane * 8 + i;
        ystartG[b * 513 + x] = run;
        outDur[(size_t)b * TXD + x] = (float)c8[i];
        run += c8[i];
    }
    if (lane == 0) ystartG[b * 513 + 512] = (unsigned)ty;
    for (int y = lane; y < ty; y += 64) pathG[b * TYD + y] = path[y];
}

// ---------------- K4: dense attn rows (f32 0/1) ----------------
__global__ __launch_bounds__(64) void k_attn(const unsigned* __restrict__ ystartG,
                                             float* __restrict__ out) {
    int x = blockIdx.x, b = blockIdx.y, lane = threadIdx.x;
    unsigned s0 = ystartG[b * 513 + x];
    unsigned s1 = ystartG[b * 513 + x + 1];
    float* row = out + E_ATTN + ((size_t)(b * TXD + x)) * TYD + lane * 32;
#pragma unroll
    for (int k = 0; k < 8; ++k) {
        unsigned y0 = (unsigned)(lane * 32 + k * 4);
        float4 o;
        o.x = (y0 + 0 >= s0 && y0 + 0 < s1) ? 1.0f : 0.0f;
        o.y = (y0 + 1 >= s0 && y0 + 1 < s1) ? 1.0f : 0.0f;
        o.z = (y0 + 2 >= s0 && y0 + 2 < s1) ? 1.0f : 0.0f;
        o.w = (y0 + 3 >= s0 && y0 + 3 < s1) ? 1.0f : 0.0f;
        *(float4*)(row + k * 4) = o;
    }
}

// ---------------- K5: m_p_dur / logs_p_dur gathers (f32) ----------------
__global__ __launch_bounds__(256) void k_gather(const float* __restrict__ m_p,
                                                const float* __restrict__ logs_p,
                                                const unsigned short* __restrict__ pathG,
                                                const unsigned* __restrict__ txty,
                                                float* __restrict__ out) {
    __shared__ unsigned short px[64];
    int yc = blockIdx.x, b = blockIdx.y;
    int y0 = yc * 64, tid = threadIdx.x;
    int lane = tid & 63, w = tid >> 6;
    int ty = (int)txty[BB + b];
    if (tid < 64) px[tid] = (y0 + tid < ty) ? pathG[b * TYD + y0 + tid] : 0;
    __syncthreads();
    bool act = (y0 + lane) < ty;
    int xx = (int)px[lane];
    for (int c = w; c < CC; c += 4) {
        float mv = act ? m_p[((size_t)b * CC + c) * TXD + xx] : 0.0f;
        float lv = act ? logs_p[((size_t)b * CC + c) * TXD + xx] : 0.0f;
        size_t oidx = ((size_t)(b * CC + c)) * TYD + y0 + lane;
        out[E_MP + oidx] = mv;
        out[E_LS + oidx] = lv;
    }
}

extern "C" void kernel_launch(void* const* d_in, const int* in_sizes, int n_in,
                              void* d_out, int out_size, void* d_ws, size_t ws_size,
                              hipStream_t stream) {
    if (out_size < E_TOTAL) return;
    if (ws_size < WS_NEED) return;
    const float* z_p    = (const float*)d_in[0];
    const float* m_p    = (const float*)d_in[1];
    const float* logs_p = (const float*)d_in[2];
    const int* xl       = (const int*)d_in[3];
    const int* yl       = (const int*)d_in[4];
    float* out = (float*)d_out;
    char* ws = (char*)d_ws;

    float* l14            = out + E_DUR;
    float* L              = out + E_ATTN;
    _Float16* Zpl         = (_Float16*)(out + E_MP);
    _Float16* Bpl         = (_Float16*)(out + E_LS);
    unsigned char* dirsG  = (unsigned char*)(out + E_LS + OFF_DIRS);
    unsigned short* pathG = (unsigned short*)(ws + WS_PATH);
    unsigned* ystartG     = (unsigned*)(ws + WS_YST);
    unsigned* txty        = (unsigned*)(ws + WS_TXTY);

    hipLaunchKernelGGL(k_prepB, dim3(16, BB), dim3(256), 0, stream,
                       logs_p, m_p, xl, yl, Bpl, l14, txty);
    hipLaunchKernelGGL(k_prepZ, dim3(16, BB), dim3(256), 0, stream, z_p, Zpl, 0);
    hipLaunchKernelGGL(k_mm, dim3(512), dim3(256), 0, stream, Zpl, Bpl, l14, txty, L, 0);
    hipLaunchKernelGGL(k_prepZ, dim3(16, BB), dim3(256), 0, stream, z_p, Zpl, 1024);
    hipLaunchKernelGGL(k_mm, dim3(512), dim3(256), 0, stream, Zpl, Bpl, l14, txty, L, 1024);
    hipLaunchKernelGGL(k_dp, dim3(BB), dim3(64), 0, stream, L, txty, dirsG, pathG, ystartG, out + E_DUR);
    hipLaunchKernelGGL(k_attn, dim3(TXD, BB), dim3(64), 0, stream, ystartG, out);
    hipLaunchKernelGGL(k_gather, dim3(TYD / 64, BB), dim3(256), 0, stream, m_p, logs_p, pathG, txty, out);
}